// Round 1
// baseline (283.403 us; speedup 1.0000x reference)
//
#include <hip/hip_runtime.h>

// WaveMaskEncoder, MFMA bf16 version — w-first contraction order.
// All 6 contractions are on distinct axes and commute. We compress the
// CONTIGUOUS axis w first and decompress w last, so the two 134-MB tensors
// (x read, out write) are accessed lane-contiguously:
//   k1: t1[bc,r,d,h] = sum_w x[bc,d,h,w] EN1[w,r]        (coalesced x reads)
//   k2: per slab (bc,r): S[d][h] -> enc(h->q, d->p) -> dec(q->h', p->d')
//   k3: out[bc,d,h,w'] = sum_r t2[bc,r,d,h] DE1[r,w']    (coalesced out writes)
//
// MFMA 16x16x32 bf16 layouts (HW-verified per docs m89/m120):
//   A[m][k]: m = lane&15, k = (lane>>4)*8 + j   (8 contiguous k per lane)
//   B[k][n]: n = lane&15, k = (lane>>4)*8 + j   (n-major, k-contig storage)
//   C/D:     col = lane&15, row = (lane>>4)*4 + reg

#define LDIM 128
#define NDIM 48
#define HW   (LDIM * LDIM)     // 16384
#define L3V  (LDIM * HW)       // 2097152

typedef __bf16 bf16x8 __attribute__((ext_vector_type(8)));
typedef float  f32x4  __attribute__((ext_vector_type(4)));
typedef unsigned short u16;

// LDS row strides (u16 units); multiples of 8 u16 = 16 B for b128 alignment.
// 136 u16 = 68 dwords: row-to-row bank step = 68%32 = 4 -> 16 rows = 2-way = free.
#define S128 136   // rows with K=128
#define S64  72    // rows with K=64

// Weight table offsets (u16 elements) inside W:
#define W_EN3T 0        // [p=48][d=128]
#define W_EN2T 6144     // [q=48][h=128]
#define W_EN1T 12288    // [r=48][w=128]
#define W_DE3T 18432    // [d=128][p=64 pad0]
#define W_DE2T 26624    // [h=128][q=64 pad0]
#define W_DE1T 34816    // [w=128][r=64 pad0]
#define W_TOT  43008

__device__ __forceinline__ u16 f2bf(float f) {   // fp32 -> bf16 RNE
    unsigned int u = __builtin_bit_cast(unsigned int, f);
    return (u16)((u + 0x7fffu + ((u >> 16) & 1u)) >> 16);
}
__device__ __forceinline__ bf16x8 frag(const u16* p) {
    return *reinterpret_cast<const bf16x8*>(p);
}
__device__ __forceinline__ f32x4 mfma16(bf16x8 a, bf16x8 b, f32x4 c) {
    return __builtin_amdgcn_mfma_f32_16x16x32_bf16(a, b, c, 0, 0, 0);
}

// ---------------------------------------------------------------- kPrep
__global__ __launch_bounds__(256) void kPrep(const float* __restrict__ EN3,
                                             const float* __restrict__ EN2,
                                             const float* __restrict__ EN1,
                                             const float* __restrict__ DE3,
                                             const float* __restrict__ DE2,
                                             const float* __restrict__ DE1,
                                             u16* __restrict__ W) {
    int i = blockIdx.x * 256 + threadIdx.x;
    if (i < 6144)       { int p = i >> 7, d = i & 127;                 W[i] = f2bf(EN3[d * 48 + p]); }
    else if (i < 12288) { int j = i - 6144;  int q = j >> 7, h = j & 127; W[i] = f2bf(EN2[h * 48 + q]); }
    else if (i < 18432) { int j = i - 12288; int r = j >> 7, w = j & 127; W[i] = f2bf(EN1[w * 48 + r]); }
    else if (i < 26624) { int j = i - 18432; int d = j >> 6, p = j & 63;  W[i] = f2bf(p < 48 ? DE3[p * 128 + d] : 0.f); }
    else if (i < 34816) { int j = i - 26624; int h = j >> 6, q = j & 63;  W[i] = f2bf(q < 48 ? DE2[q * 128 + h] : 0.f); }
    else if (i < 43008) { int j = i - 34816; int w = j >> 6, r = j & 63;  W[i] = f2bf(r < 48 ? DE1[r * 128 + w] : 0.f); }
}

// ---------------------------------------------------------------- kA (k1)
// t1[(bc*48+r)][d][h] = sum_w x[bc][d][h][w] * EN1[w][r]
// grid (d=128, bc=16), block 256 = 4 waves. Per block: tile [h=128][w=128].
// x reads are lane-contiguous float4 (1 KB/wave/instr). A from LDS, B = EN1t
// from global (12 KB, L2-hot). One barrier, no output staging.
__global__ __launch_bounds__(256) void kA(const float* __restrict__ x,
                                          const u16* __restrict__ W,
                                          u16* __restrict__ t1) {
    __shared__ u16 lx[128 * S128];   // [h][w] bf16 (A-operand rows)
    const int bc = blockIdx.y;
    const int d  = blockIdx.x;
    const int t = threadIdx.x, lane = t & 63, wv = t >> 6, quad = lane >> 4;
    const int row = lane & 15, kof = quad * 8;

    // Stage x[bc][d][:][:] -> lx[h][w]: coalesced float4 reads, packed b64 writes.
    {
        const float* xp = x + (size_t)bc * L3V + (size_t)d * HW;
        for (int i = 0; i < 16; ++i) {
            int f = i * 1024 + t * 4;          // flat fp32 index in [h][w] tile
            float4 v = *reinterpret_cast<const float4*>(xp + f);
            int h = f >> 7, w = f & 127;
            uint2 pk;
            pk.x = (unsigned)f2bf(v.x) | ((unsigned)f2bf(v.y) << 16);
            pk.y = (unsigned)f2bf(v.z) | ((unsigned)f2bf(v.w) << 16);
            *reinterpret_cast<uint2*>(lx + h * S128 + w) = pk;
        }
    }
    __syncthreads();
    // wave wv owns h-tiles {2wv, 2wv+1}; n(r)-tiles 0..2; K=128 in 4 steps.
    const int h0 = wv * 32;
    f32x4 acc[2][3] = {};
    for (int kk = 0; kk < 4; ++kk) {
        bf16x8 b[3];
        for (int n = 0; n < 3; ++n)
            b[n] = frag(W + W_EN1T + (n * 16 + row) * 128 + kk * 32 + kof);
        for (int m = 0; m < 2; ++m) {
            bf16x8 a = frag(lx + (h0 + m * 16 + row) * S128 + kk * 32 + kof);
            for (int n = 0; n < 3; ++n) acc[m][n] = mfma16(a, b[n], acc[m][n]);
        }
    }
    // C[m=h][n=r]: 4 regs = 4 consecutive h = contiguous in t1 -> packed 8B stores
    // (16 r-slabs x 32B segments per instr; t1 writes are only 25 MB total).
    u16* op = t1 + (size_t)bc * 48 * HW + d * 128;
    for (int m = 0; m < 2; ++m)
        for (int n = 0; n < 3; ++n) {
            int r = n * 16 + row;
            int h = h0 + m * 16 + quad * 4;
            uint2 pk;
            pk.x = (unsigned)f2bf(acc[m][n][0]) | ((unsigned)f2bf(acc[m][n][1]) << 16);
            pk.y = (unsigned)f2bf(acc[m][n][2]) | ((unsigned)f2bf(acc[m][n][3]) << 16);
            *reinterpret_cast<uint2*>(op + (size_t)r * HW + h) = pk;
        }
}

// ---------------------------------------------------------------- kMid (k2)
// Per slab (bc,r): S[d][h] (from t1) -> T1[d][q] -> E[p][q] -> V[h'][p] -> O[d'][h'] (u2)
// Identical structure to the verified kMid; only the weight tables rotate:
//   G1 B: EN2t (contract h), G2 A: EN3t (contract d),
//   G3 A: DE2t (decode q->h'), G4 A: DE3t (decode p->d').
__global__ __launch_bounds__(256) void kMid(const u16* __restrict__ t1,
                                            const u16* __restrict__ W,
                                            u16* __restrict__ u2) {
    __shared__ u16 pool[26624];
    u16* lT = pool;            // [q=48][d=128] stride S128 : 6528
    u16* lE = pool + 6528;     // [p=48][q=64]  stride S64  : 3456 (ends 9984)
    u16* lO = pool;            // [d'=128][h'=128] stride S128 : 17408 (reuses lT+lE after G3)
    u16* lU = pool + 17408;    // [h'=128][p=64] stride S64 : 9216 (ends 26624)

    const int slab = blockIdx.x;                 // bc*48 + r
    const int t = threadIdx.x, lane = t & 63, wv = t >> 6, quad = lane >> 4;
    const int row = lane & 15, kof = quad * 8;
    const u16* Sg = t1 + (size_t)slab * HW;      // S[d][h], row stride 128

    // zero-fill K-padding of lE (q=48..63) and lU (p=48..63)
    for (int i = t; i < 48 * 16; i += 256)  { int p = i >> 4; lE[p * S64 + 48 + (i & 15)] = 0; }
    for (int i = t; i < 128 * 16; i += 256) { int h = i >> 4; lU[h * S64 + 48 + (i & 15)] = 0; }

    // ---- G1: T1[d][q] = sum_h S[d][h] * EN2[h][q];  wave: d-rows [wv*32, +32)
    {
        const int d0 = wv * 32;
        f32x4 acc[2][3] = {};
        for (int kk = 0; kk < 4; ++kk) {
            bf16x8 b[3];
            for (int n = 0; n < 3; ++n)
                b[n] = frag(W + W_EN2T + (n * 16 + row) * 128 + kk * 32 + kof);
            for (int m = 0; m < 2; ++m) {
                bf16x8 a = frag(Sg + (d0 + m * 16 + row) * 128 + kk * 32 + kof);
                for (int n = 0; n < 3; ++n) acc[m][n] = mfma16(a, b[n], acc[m][n]);
            }
        }
        // write lT[q][d]; 4 regs = 4 consecutive d -> packed 8B write
        for (int m = 0; m < 2; ++m)
            for (int n = 0; n < 3; ++n) {
                int q = n * 16 + row;
                int dd = d0 + m * 16 + quad * 4;
                uint2 pk;
                pk.x = (unsigned)f2bf(acc[m][n][0]) | ((unsigned)f2bf(acc[m][n][1]) << 16);
                pk.y = (unsigned)f2bf(acc[m][n][2]) | ((unsigned)f2bf(acc[m][n][3]) << 16);
                *reinterpret_cast<uint2*>(lT + q * S128 + dd) = pk;
            }
    }
    __syncthreads();
    // ---- G2: E[p][q] = sum_d EN3[d][p] * T1[d][q];  waves 0..2, m-tile = wv
    if (wv < 3) {
        const int p0 = wv * 16;
        f32x4 acc[3] = {};
        for (int kk = 0; kk < 4; ++kk) {
            bf16x8 a = frag(W + W_EN3T + (p0 + row) * 128 + kk * 32 + kof);
            for (int n = 0; n < 3; ++n) {
                bf16x8 b = frag(lT + (n * 16 + row) * S128 + kk * 32 + kof);
                acc[n] = mfma16(a, b, acc[n]);
            }
        }
        for (int n = 0; n < 3; ++n)
            for (int j = 0; j < 4; ++j)
                lE[(p0 + quad * 4 + j) * S64 + n * 16 + row] = f2bf(acc[n][j]);
    }
    __syncthreads();
    // ---- G3: V[h'][p] = sum_q DE2[q][h'] * E[p][q];  wave: h'-rows [wv*32, +32), K=64
    {
        const int h0 = wv * 32;
        f32x4 acc[2][3] = {};
        for (int kk = 0; kk < 2; ++kk) {
            bf16x8 b[3];
            for (int n = 0; n < 3; ++n)
                b[n] = frag(lE + (n * 16 + row) * S64 + kk * 32 + kof);
            for (int m = 0; m < 2; ++m) {
                bf16x8 a = frag(W + W_DE2T + (h0 + m * 16 + row) * 64 + kk * 32 + kof);
                for (int n = 0; n < 3; ++n) acc[m][n] = mfma16(a, b[n], acc[m][n]);
            }
        }
        for (int m = 0; m < 2; ++m)
            for (int n = 0; n < 3; ++n)
                for (int j = 0; j < 4; ++j)
                    lU[(h0 + m * 16 + quad * 4 + j) * S64 + n * 16 + row] = f2bf(acc[m][n][j]);
    }
    __syncthreads();
    // ---- G4: O[d'][h'] = sum_p DE3[p][d'] * V[h'][p];  wave 2x2 tiling, K=64
    {
        const int m0 = (wv & 1) * 64, n0 = (wv >> 1) * 64;
        f32x4 acc[4][4] = {};
        for (int kk = 0; kk < 2; ++kk) {
            bf16x8 b[4];
            for (int n = 0; n < 4; ++n)
                b[n] = frag(lU + (n0 + n * 16 + row) * S64 + kk * 32 + kof);
            for (int m = 0; m < 4; ++m) {
                bf16x8 a = frag(W + W_DE3T + (m0 + m * 16 + row) * 64 + kk * 32 + kof);
                for (int n = 0; n < 4; ++n) acc[m][n] = mfma16(a, b[n], acc[m][n]);
            }
        }
        // write lO[d'][h'] (overlaps lT/lE which are dead; lU untouched)
        for (int m = 0; m < 4; ++m)
            for (int n = 0; n < 4; ++n)
                for (int j = 0; j < 4; ++j)
                    lO[(m0 + m * 16 + quad * 4 + j) * S128 + n0 + n * 16 + row] = f2bf(acc[m][n][j]);
    }
    __syncthreads();
    // store u2 slab [d'][h'] coalesced
    u16* up = u2 + (size_t)slab * HW;
    for (int i = 0; i < 8; ++i) {
        int idx = t + i * 256;          // 0..2047
        int h = idx >> 4, c = (idx & 15) * 8;
        *reinterpret_cast<float4*>(up + h * 128 + c) =
            *reinterpret_cast<const float4*>(lO + h * S128 + c);
    }
}

// ---------------------------------------------------------------- kF (k3)
// out[bc][dh][w'] = sum_r DE1[r][w'] * u2[(bc*48+r)][dh]   (fp32 out), K=48 pad 64
// A = staged u2 tile [m=dh][k=r] (LDS), B = DE1t[w'][r] in registers ->
// C cols = w' = contiguous output axis (coalesced 64B-segment stores).
__global__ __launch_bounds__(256) void kF(const u16* __restrict__ u2,
                                          const u16* __restrict__ W,
                                          float* __restrict__ out) {
    __shared__ u16 lb[128 * S64];    // [dh][r64]  (A-operand layout)
    const int bc = blockIdx.y, dh0 = blockIdx.x * 128;
    const int t = threadIdx.x, lane = t & 63, wv = t >> 6, quad = lane >> 4;
    const int row = lane & 15, kof = quad * 8;
    const int m0 = (wv & 1) * 64, n0 = (wv >> 1) * 64;

    // B-frags (DE1t[w'][r]) in registers: 4 n-tiles x 2 k-steps
    bf16x8 bfr[4][2];
    for (int n = 0; n < 4; ++n)
        for (int kk = 0; kk < 2; ++kk)
            bfr[n][kk] = frag(W + W_DE1T + (n0 + n * 16 + row) * 64 + kk * 32 + kof);

    // Stage u2 -> lb[dh][r], lanes along r (conflict-free LDS); r>=48 -> zeros
    {
        const int r   = t & 63;
        const int dhb = (t >> 6) * 32;
        const u16* sp = u2 + ((size_t)(bc * 48) + r) * HW + dh0 + dhb;
        const bool valid = r < 48;
        for (int i = 0; i < 4; ++i) {
            u16 v[8] = {0, 0, 0, 0, 0, 0, 0, 0};
            if (valid) *reinterpret_cast<float4*>(v) = *reinterpret_cast<const float4*>(sp + i * 8);
            for (int j = 0; j < 8; ++j) lb[(dhb + i * 8 + j) * S64 + r] = v[j];
        }
    }
    __syncthreads();
    f32x4 acc[4][4] = {};
    for (int kk = 0; kk < 2; ++kk) {
        bf16x8 a[4];
        for (int m = 0; m < 4; ++m)
            a[m] = frag(lb + (m0 + m * 16 + row) * S64 + kk * 32 + kof);
        for (int m = 0; m < 4; ++m)
            for (int n = 0; n < 4; ++n) acc[m][n] = mfma16(a[m], bfr[n][kk], acc[m][n]);
    }
    // fp32 stores straight from C-frags: rows dh (512 B apart), cols w' contiguous
    float* ob = out + (size_t)bc * L3V + (size_t)dh0 * 128;
    for (int m = 0; m < 4; ++m)
        for (int n = 0; n < 4; ++n)
            for (int j = 0; j < 4; ++j) {
                int dh = m0 + m * 16 + quad * 4 + j;
                int wp = n0 + n * 16 + row;
                ob[(size_t)dh * 128 + wp] = acc[m][n][j];
            }
}

// ---------------------------------------------------------------- launch
extern "C" void kernel_launch(void* const* d_in, const int* in_sizes, int n_in,
                              void* d_out, int out_size, void* d_ws, size_t ws_size,
                              hipStream_t stream) {
    const float* x   = (const float*)d_in[0];
    const float* EN3 = (const float*)d_in[1];
    const float* EN2 = (const float*)d_in[2];
    const float* EN1 = (const float*)d_in[3];
    const float* DE3 = (const float*)d_in[4];
    const float* DE2 = (const float*)d_in[5];
    const float* DE1 = (const float*)d_in[6];
    float* out = (float*)d_out;

    // ws (bytes): t1 bf16 @0 (25165824), u2 bf16 @25165824 (25165824), W @50331648 (86016)
    u16* t1 = (u16*)d_ws;
    u16* u2 = (u16*)((char*)d_ws + 25165824);
    u16* W  = (u16*)((char*)d_ws + 50331648);

    kPrep<<<dim3(168),     256, 0, stream>>>(EN3, EN2, EN1, DE3, DE2, DE1, W);
    kA   <<<dim3(128, 16), 256, 0, stream>>>(x, W, t1);
    kMid <<<dim3(768),     256, 0, stream>>>(t1, W, u2);
    kF   <<<dim3(128, 16), 256, 0, stream>>>(u2, W, out);
}

// Round 2
// 279.607 us; speedup vs baseline: 1.0136x; 1.0136x over previous
//
#include <hip/hip_runtime.h>

// WaveMaskEncoder — M-collapsed 3-stage pipeline.
// Key algebraic identity: EN3 (encode d->p) and DE3 (decode p->d') compose:
//   M[d'][d] = sum_p EN3[d,p] DE3[p,d']   (128x128, built once in kPrep)
// Pipeline:
//   kEnc: t[bc,d,q,r] = EN2^T . (x[bc,d,:,:] . EN1)      (134 MB R, 9.4 MB W)
//   kM  : u[bc,d',q,r] = sum_d M[d'][d] t[bc,d,q,r]      (9.4 R, 9.4 W)
//   kDec: out[bc,d',h',w'] = (DE2^T . u[bc,d']) . DE1    (9.4 R, 134 MB W)
//
// MFMA 16x16x32 bf16 layouts (HW-verified per docs m89/m120):
//   A[m][k]: m = lane&15, k = (lane>>4)*8 + j   (8 contiguous k per lane)
//   B[k][n]: n = lane&15, k = (lane>>4)*8 + j   (n-major, k-contig storage)
//   C/D:     col = lane&15, row = (lane>>4)*4 + reg

#define LDIM 128
#define NDIM 48
#define HW   (LDIM * LDIM)     // 16384
#define L3V  (LDIM * HW)       // 2097152
#define QR   2304              // 48*48

typedef __bf16 bf16x8 __attribute__((ext_vector_type(8)));
typedef float  f32x4  __attribute__((ext_vector_type(4)));
typedef unsigned short u16;

// LDS row strides (u16 units); multiples of 8 u16 = 16 B for b128 alignment.
// 136 u16 = 68 dwords: row-to-row bank step = 68%32 = 4 -> 16 rows = 2-way = free.
// 72 u16 = 36 dwords: step 4 -> same property.
#define S128 136
#define S64  72

// Weight table offsets (u16 elements) inside W:
#define W_EN3T 0        // [p=48][d=128] (kept for layout stability; unused)
#define W_EN2T 6144     // [q=48][h=128]
#define W_EN1T 12288    // [r=48][w=128]
#define W_DE3T 18432    // [d=128][p=64 pad0] (unused)
#define W_DE2T 26624    // [h=128][q=64 pad0]
#define W_DE1T 34816    // [w=128][r=64 pad0]
#define W_M    43008    // Mt[d'=128][d=128] (A-operand layout, k=d contig)
#define W_TOT  59392

__device__ __forceinline__ u16 f2bf(float f) {   // fp32 -> bf16 RNE
    unsigned int u = __builtin_bit_cast(unsigned int, f);
    return (u16)((u + 0x7fffu + ((u >> 16) & 1u)) >> 16);
}
__device__ __forceinline__ bf16x8 frag(const u16* p) {
    return *reinterpret_cast<const bf16x8*>(p);
}
__device__ __forceinline__ f32x4 mfma16(bf16x8 a, bf16x8 b, f32x4 c) {
    return __builtin_amdgcn_mfma_f32_16x16x32_bf16(a, b, c, 0, 0, 0);
}

// ---------------------------------------------------------------- kPrep
// Builds bf16 weight tables + M = EN3 . DE3 (fp32 accumulate, bf16 round).
__global__ __launch_bounds__(256) void kPrep(const float* __restrict__ EN3,
                                             const float* __restrict__ EN2,
                                             const float* __restrict__ EN1,
                                             const float* __restrict__ DE3,
                                             const float* __restrict__ DE2,
                                             const float* __restrict__ DE1,
                                             u16* __restrict__ W) {
    int i = blockIdx.x * 256 + threadIdx.x;
    if (i < 6144)       { int p = i >> 7, d = i & 127;                 W[i] = f2bf(EN3[d * 48 + p]); }
    else if (i < 12288) { int j = i - 6144;  int q = j >> 7, h = j & 127; W[i] = f2bf(EN2[h * 48 + q]); }
    else if (i < 18432) { int j = i - 12288; int r = j >> 7, w = j & 127; W[i] = f2bf(EN1[w * 48 + r]); }
    else if (i < 26624) { int j = i - 18432; int d = j >> 6, p = j & 63;  W[i] = f2bf(p < 48 ? DE3[p * 128 + d] : 0.f); }
    else if (i < 34816) { int j = i - 26624; int h = j >> 6, q = j & 63;  W[i] = f2bf(q < 48 ? DE2[q * 128 + h] : 0.f); }
    else if (i < 43008) { int j = i - 34816; int w = j >> 6, r = j & 63;  W[i] = f2bf(r < 48 ? DE1[r * 128 + w] : 0.f); }
    else if (i < 59392) {
        int j = i - 43008; int dp = j >> 7, d = j & 127;
        float s = 0.f;
        for (int p = 0; p < 48; ++p) s += EN3[d * 48 + p] * DE3[p * 128 + dp];
        W[i] = f2bf(s);
    }
}

// ---------------------------------------------------------------- kEnc
// t[(bc*128+d)][q][r] = sum_h EN2[h][q] * (sum_w x[bc][d][h][w] EN1[w][r])
// grid (d=128, bc=16), block 256 = 4 waves. Coalesced x reads; 2 barriers.
__global__ __launch_bounds__(256) void kEnc(const float* __restrict__ x,
                                            const u16* __restrict__ W,
                                            u16* __restrict__ t) {
    __shared__ u16 lS[128 * S128];   // [h][w]  (A rows, k=w contig)
    __shared__ u16 lT[48 * S128];    // [r][h]  (B n-major, k=h contig)
    const int bc = blockIdx.y, d = blockIdx.x;
    const int tid = threadIdx.x, lane = tid & 63, wv = tid >> 6, quad = lane >> 4;
    const int row = lane & 15, kof = quad * 8;

    // Stage x[bc][d][:][:] -> lS[h][w]: coalesced float4 reads, packed b64 writes.
    {
        const float* xp = x + (size_t)bc * L3V + (size_t)d * HW;
        for (int i = 0; i < 16; ++i) {
            int f = i * 1024 + tid * 4;
            float4 v = *reinterpret_cast<const float4*>(xp + f);
            int h = f >> 7, w = f & 127;
            uint2 pk;
            pk.x = (unsigned)f2bf(v.x) | ((unsigned)f2bf(v.y) << 16);
            pk.y = (unsigned)f2bf(v.z) | ((unsigned)f2bf(v.w) << 16);
            *reinterpret_cast<uint2*>(lS + h * S128 + w) = pk;
        }
    }
    __syncthreads();
    // G_a: T[h][r] = sum_w S[h][w] * EN1[w][r]; wave: h-rows [wv*32,+32)
    {
        const int h0 = wv * 32;
        f32x4 acc[2][3] = {};
        for (int kk = 0; kk < 4; ++kk) {
            bf16x8 b[3];
            for (int n = 0; n < 3; ++n)
                b[n] = frag(W + W_EN1T + (n * 16 + row) * 128 + kk * 32 + kof);
            for (int m = 0; m < 2; ++m) {
                bf16x8 a = frag(lS + (h0 + m * 16 + row) * S128 + kk * 32 + kof);
                for (int n = 0; n < 3; ++n) acc[m][n] = mfma16(a, b[n], acc[m][n]);
            }
        }
        // write lT[r][h]; 4 regs = 4 consecutive h -> packed 8B write
        for (int m = 0; m < 2; ++m)
            for (int n = 0; n < 3; ++n) {
                int r = n * 16 + row, h = h0 + m * 16 + quad * 4;
                uint2 pk;
                pk.x = (unsigned)f2bf(acc[m][n][0]) | ((unsigned)f2bf(acc[m][n][1]) << 16);
                pk.y = (unsigned)f2bf(acc[m][n][2]) | ((unsigned)f2bf(acc[m][n][3]) << 16);
                *reinterpret_cast<uint2*>(lT + r * S128 + h) = pk;
            }
    }
    __syncthreads();
    // G_b: A[q][r] = sum_h EN2[h][q] * T[h][r]; waves 0..2, m-tile = wv
    if (wv < 3) {
        const int q0 = wv * 16;
        f32x4 acc[3] = {};
        for (int kk = 0; kk < 4; ++kk) {
            bf16x8 a = frag(W + W_EN2T + (q0 + row) * 128 + kk * 32 + kof);
            for (int n = 0; n < 3; ++n) {
                bf16x8 b = frag(lT + (n * 16 + row) * S128 + kk * 32 + kof);
                acc[n] = mfma16(a, b, acc[n]);
            }
        }
        u16* tp = t + (size_t)(bc * 128 + d) * QR;
        for (int n = 0; n < 3; ++n)
            for (int j = 0; j < 4; ++j)
                tp[(q0 + quad * 4 + j) * 48 + n * 16 + row] = f2bf(acc[n][j]);
    }
}

// ---------------------------------------------------------------- kM
// u[bc][d'][q][r] = sum_d M[d'][d] * t[bc][d][q][r]
// grid (qr-tiles 36, bc 16), block 256. GEMM m=d'(128) x n=qr(64), K=128.
__global__ __launch_bounds__(256) void kM(const u16* __restrict__ t,
                                          const u16* __restrict__ W,
                                          u16* __restrict__ u) {
    __shared__ u16 lB[64 * S128];    // [qr_local][d]  (B n-major, k=d contig)
    const int bc = blockIdx.y, qr0 = blockIdx.x * 64;
    const int tid = threadIdx.x, lane = tid & 63, wv = tid >> 6, quad = lane >> 4;
    const int row = lane & 15, kof = quad * 8;

    // stage t tile [d=128][qr 64] -> lB[qr][d] (transpose via u16 writes; 16 KB)
    {
        const u16* tp = t + (size_t)bc * (128 * QR) + qr0 + (tid & 7) * 8;
        const int d0 = tid >> 3;                  // 0..31
        for (int g = 0; g < 4; ++g) {
            int dd = d0 + g * 32;
            u16 v[8];
            *reinterpret_cast<float4*>(v) = *reinterpret_cast<const float4*>(tp + (size_t)dd * QR);
            for (int j = 0; j < 8; ++j) lB[((tid & 7) * 8 + j) * S128 + dd] = v[j];
        }
    }
    __syncthreads();
    const int m0 = wv * 32;
    f32x4 acc[2][4] = {};
    for (int kk = 0; kk < 4; ++kk) {
        bf16x8 a[2], b[4];
        for (int n = 0; n < 4; ++n)
            b[n] = frag(lB + (n * 16 + row) * S128 + kk * 32 + kof);
        for (int m = 0; m < 2; ++m)
            a[m] = frag(W + W_M + (m0 + m * 16 + row) * 128 + kk * 32 + kof);
        for (int m = 0; m < 2; ++m)
            for (int n = 0; n < 4; ++n) acc[m][n] = mfma16(a[m], b[n], acc[m][n]);
    }
    u16* up = u + (size_t)bc * (128 * QR) + qr0;
    for (int m = 0; m < 2; ++m)
        for (int n = 0; n < 4; ++n)
            for (int j = 0; j < 4; ++j) {
                int dp = m0 + m * 16 + quad * 4 + j;
                up[(size_t)dp * QR + n * 16 + row] = f2bf(acc[m][n][j]);
            }
}

// ---------------------------------------------------------------- kDec
// out[bc][d'][h'][w'] = sum_r (sum_q DE2[q][h'] u[bc][d'][q][r]) * DE1[r][w']
// grid (d'=128, bc=16), block 256 = 4 waves. 2 barriers; direct fp32 stores.
__global__ __launch_bounds__(256) void kDec(const u16* __restrict__ u,
                                            const u16* __restrict__ W,
                                            float* __restrict__ out) {
    __shared__ u16 lU[48 * S64];     // [r][q pad64]  (B n-major, k=q contig)
    __shared__ u16 lV[128 * S64];    // [h'][r pad64] (A rows, k=r contig)
    const int bc = blockIdx.y, dp = blockIdx.x;
    const int tid = threadIdx.x, lane = tid & 63, wv = tid >> 6, quad = lane >> 4;
    const int row = lane & 15, kof = quad * 8;

    // zero K-padding (q=48..63 of lU, r=48..63 of lV)
    for (int i = tid; i < 48 * 16; i += 256)  lU[(i >> 4) * S64 + 48 + (i & 15)] = 0;
    for (int i = tid; i < 128 * 16; i += 256) lV[(i >> 4) * S64 + 48 + (i & 15)] = 0;
    // stage u[bc][d'][q][r] (4.6 KB) -> lU[r][q] transposed
    {
        const u16* sp = u + (size_t)(bc * 128 + dp) * QR;
        for (int i = tid; i < 288; i += 256) {
            u16 v[8];
            *reinterpret_cast<float4*>(v) = *reinterpret_cast<const float4*>(sp + i * 8);
            int q = i / 6, rb = (i % 6) * 8;
            for (int j = 0; j < 8; ++j) lU[(rb + j) * S64 + q] = v[j];
        }
    }
    __syncthreads();
    // G_a: V[h'][r] = sum_q DE2[q][h'] * u[q][r]; wave: h'-rows [wv*32,+32), K=64
    {
        const int h0 = wv * 32;
        f32x4 acc[2][3] = {};
        for (int kk = 0; kk < 2; ++kk) {
            bf16x8 b[3];
            for (int n = 0; n < 3; ++n)
                b[n] = frag(lU + (n * 16 + row) * S64 + kk * 32 + kof);
            for (int m = 0; m < 2; ++m) {
                bf16x8 a = frag(W + W_DE2T + (h0 + m * 16 + row) * 64 + kk * 32 + kof);
                for (int n = 0; n < 3; ++n) acc[m][n] = mfma16(a, b[n], acc[m][n]);
            }
        }
        for (int m = 0; m < 2; ++m)
            for (int n = 0; n < 3; ++n)
                for (int j = 0; j < 4; ++j)
                    lV[(h0 + m * 16 + quad * 4 + j) * S64 + n * 16 + row] = f2bf(acc[m][n][j]);
    }
    __syncthreads();
    // G_b: out[h'][w'] = sum_r V[h'][r] * DE1[r][w']; K=64, direct fp32 stores
    {
        const int h0 = wv * 32;
        f32x4 acc[2][8] = {};
        for (int kk = 0; kk < 2; ++kk) {
            bf16x8 a[2], b[8];
            for (int n = 0; n < 8; ++n)
                b[n] = frag(W + W_DE1T + (n * 16 + row) * 64 + kk * 32 + kof);
            for (int m = 0; m < 2; ++m)
                a[m] = frag(lV + (h0 + m * 16 + row) * S64 + kk * 32 + kof);
            for (int m = 0; m < 2; ++m)
                for (int n = 0; n < 8; ++n) acc[m][n] = mfma16(a[m], b[n], acc[m][n]);
        }
        float* ob = out + (size_t)bc * L3V + (size_t)dp * HW;
        for (int m = 0; m < 2; ++m)
            for (int n = 0; n < 8; ++n)
                for (int j = 0; j < 4; ++j)
                    ob[(h0 + m * 16 + quad * 4 + j) * 128 + n * 16 + row] = acc[m][n][j];
    }
}

// ---------------------------------------------------------------- launch
extern "C" void kernel_launch(void* const* d_in, const int* in_sizes, int n_in,
                              void* d_out, int out_size, void* d_ws, size_t ws_size,
                              hipStream_t stream) {
    const float* x   = (const float*)d_in[0];
    const float* EN3 = (const float*)d_in[1];
    const float* EN2 = (const float*)d_in[2];
    const float* EN1 = (const float*)d_in[3];
    const float* DE3 = (const float*)d_in[4];
    const float* DE2 = (const float*)d_in[5];
    const float* DE1 = (const float*)d_in[6];
    float* out = (float*)d_out;

    // ws (bytes): t @0 (9,437,184), u @9437184 (9,437,184), W @18874368 (118,784)
    u16* t = (u16*)d_ws;
    u16* u = (u16*)((char*)d_ws + 9437184);
    u16* W = (u16*)((char*)d_ws + 18874368);

    kPrep<<<dim3(232),     256, 0, stream>>>(EN3, EN2, EN1, DE3, DE2, DE1, W);
    kEnc <<<dim3(128, 16), 256, 0, stream>>>(x, W, t);
    kM   <<<dim3(36, 16),  256, 0, stream>>>(t, W, u);
    kDec <<<dim3(128, 16), 256, 0, stream>>>(u, W, out);
}